// Round 6
// baseline (135.203 us; speedup 1.0000x reference)
//
#include <hip/hip_runtime.h>
#include <hip/hip_bf16.h>
#include <math.h>

// Problem: B=16, T=2048, D=256, gamma=0.9
// out[b,t,d] = S2[t,d] * (x@Wq)[b,t,d]
// S2[t,d] = S[8d + (t>>8)][t&255]   (reshape-scramble)
// S[t>=1] = A[t], S[0] = A[1],  A[t] = gamma*A[t-1] + g[t], A[0]=0 (g[0] := 0)
// g = y @ Wk,  y[t,:] = sum_b w[b,t]*x[b,t,:],  w[b,t] = x[b,t,:] . rowsum(Wv)
//
// R6: 5 kernels. k_gs fuses (y@WkT) MFMA + 8-step local scans (g never hits
// memory). k_S2P rewritten: 32 blocks, incremental carry prefix (o const per
// block), LDS transpose -> coalesced S2 writes. qgemm = R3's proven 512-block.

#define GAMMA_F 0.9f
#define T_LEN 2048
#define D_DIM 256
#define B_DIM 16

typedef __attribute__((ext_vector_type(8))) short bf16x8;
typedef __attribute__((ext_vector_type(16))) float f32x16;

__device__ inline ushort f2bf(float f) {
    union { float f; unsigned u; } v; v.f = f;
    unsigned r = (v.u + 0x7FFFu + ((v.u >> 16) & 1u)) >> 16;  // RNE
    return (ushort)r;
}

// ---------- K1: prep — WqT, WkT (bf16 [n][k]) + wv_sum ----------
__global__ __launch_bounds__(256) void k_prep(const float* __restrict__ Wq,
                                              const float* __restrict__ Wk,
                                              const float* __restrict__ Wv,
                                              ushort* __restrict__ WqT,
                                              ushort* __restrict__ WkT,
                                              float* __restrict__ wv_sum) {
    int bid = blockIdx.x;
    int tid = threadIdx.x;
    if (bid < 32) {
        __shared__ float tile[64][68];
        const float* W = (bid < 16) ? Wq : Wk;
        ushort* WT = (bid < 16) ? WqT : WkT;
        int b = bid & 15;
        int k0 = (b & 3) * 64;
        int n0 = (b >> 2) * 64;
        int r = tid >> 4;            // 0..15
        int c4 = (tid & 15) * 4;     // 0..60
#pragma unroll
        for (int i = 0; i < 4; ++i) {
            float4 v = *(const float4*)(W + (size_t)(k0 + r + 16 * i) * D_DIM + n0 + c4);
            *(float4*)&tile[r + 16 * i][c4] = v;
        }
        __syncthreads();
        int n = tid >> 2;            // 0..63
        int j0 = (tid & 3) * 16;     // 0..48
        ushort tmp[16];
#pragma unroll
        for (int i = 0; i < 16; ++i) tmp[i] = f2bf(tile[j0 + i][n]);
        ushort* dst = WT + (size_t)(n0 + n) * D_DIM + k0 + j0;
#pragma unroll
        for (int i = 0; i < 16; ++i) dst[i] = tmp[i];
    } else {
        int j = (bid - 32) * 64 + (tid >> 2);
        int q = tid & 3;
        const float4* row4 = (const float4*)(Wv + (size_t)j * D_DIM + q * 64);
        float s = 0.f;
#pragma unroll
        for (int i = 0; i < 16; ++i) {
            float4 v = row4[i];
            s += v.x + v.y + v.z + v.w;
        }
        s += __shfl_xor(s, 1, 64);
        s += __shfl_xor(s, 2, 64);
        if (q == 0) wv_sum[j] = s;
    }
}

// ---------- K2: y (bf16) + xbf ----------
__global__ __launch_bounds__(256) void k_y(const float* __restrict__ x,
                                           const float* __restrict__ wv_sum,
                                           ushort* __restrict__ ybf,
                                           ushort* __restrict__ xbf) {
    int t = blockIdx.x;
    int d = threadIdx.x;
    float wvd = wv_sum[d];
    float xr[B_DIM];
#pragma unroll
    for (int b = 0; b < B_DIM; ++b)
        xr[b] = x[((size_t)b * T_LEN + t) * D_DIM + d];
#pragma unroll
    for (int b = 0; b < B_DIM; ++b)
        xbf[((size_t)b * T_LEN + t) * D_DIM + d] = f2bf(xr[b]);

    __shared__ float red[B_DIM][4];
    int wave = d >> 6, lane = d & 63;
#pragma unroll
    for (int b = 0; b < B_DIM; ++b) {
        float p = xr[b] * wvd;
        for (int o = 32; o > 0; o >>= 1) p += __shfl_down(p, o, 64);
        if (lane == 0) red[b][wave] = p;
    }
    __syncthreads();
    float yv = 0.f;
#pragma unroll
    for (int b = 0; b < B_DIM; ++b) {
        float wb = red[b][0] + red[b][1] + red[b][2] + red[b][3];
        yv += wb * xr[b];
    }
    ybf[(size_t)t * D_DIM + d] = f2bf(yv);
}

// ---------- K3: fused  C = ybf @ WkT^T  +  8-step local scans -> loc, carry ----------
// 32 blocks; block mt covers t in [mt*64, mt*64+64), all 256 n.
// 4 waves side-by-side in n (w = n-quadrant); each wave: 2(mi) x 2(ni) mfma 32x32x16.
// A staged in LDS (swizzled); B fragments direct from L2-resident WkT (128 KB).
// C round-trips through 64 KB LDS (aliased over As) for the t-direction scan.
__global__ __launch_bounds__(256) void k_gs(const ushort* __restrict__ ybf,
                                            const ushort* __restrict__ WkT,
                                            float* __restrict__ loc,
                                            float* __restrict__ carry) {
    __shared__ char smem[65536];
    ushort* As = (ushort*)smem;          // 32 KB: [s2h=0..31][r^swz=0..63][8]
    float* Cs = (float*)smem;            // 64 KB: [t_loc=0..63][n=0..255]
    int mt = blockIdx.x;                 // 0..31
    int tid = threadIdx.x, lane = tid & 63, w = tid >> 6;
    int l31 = lane & 31, lh = lane >> 5;

    // stage A (ybf rows mt*64..+64, full K)
#pragma unroll
    for (int i = 0; i < 8; ++i) {
        int slot = tid + 256 * i;        // 0..2047
        int r = slot >> 5;               // 0..63
        int s2h = slot & 31;             // 0..31
        int rs = r ^ (s2h & 7);
        *(bf16x8*)&As[(s2h * 64 + rs) * 8] =
            *(const bf16x8*)&ybf[(size_t)(mt * 64 + r) * D_DIM + s2h * 8];
    }
    __syncthreads();

    f32x16 acc[2][2];
#pragma unroll
    for (int i = 0; i < 2; ++i)
#pragma unroll
        for (int j = 0; j < 2; ++j)
#pragma unroll
            for (int e = 0; e < 16; ++e) acc[i][j][e] = 0.f;

    const ushort* bq = WkT + (size_t)(w * 64 + l31) * D_DIM + lh * 8;
#pragma unroll
    for (int s = 0; s < 16; ++s) {
        int s2h = s * 2 + lh;
        bf16x8 a0 = *(bf16x8*)&As[(s2h * 64 + (l31 ^ (s2h & 7))) * 8];
        bf16x8 a1 = *(bf16x8*)&As[(s2h * 64 + ((32 + l31) ^ (s2h & 7))) * 8];
        bf16x8 b0 = *(const bf16x8*)(bq + s * 16);
        bf16x8 b1 = *(const bf16x8*)(bq + 32 * D_DIM + s * 16);
        acc[0][0] = __builtin_amdgcn_mfma_f32_32x32x16_bf16(a0, b0, acc[0][0], 0, 0, 0);
        acc[0][1] = __builtin_amdgcn_mfma_f32_32x32x16_bf16(a0, b1, acc[0][1], 0, 0, 0);
        acc[1][0] = __builtin_amdgcn_mfma_f32_32x32x16_bf16(a1, b0, acc[1][0], 0, 0, 0);
        acc[1][1] = __builtin_amdgcn_mfma_f32_32x32x16_bf16(a1, b1, acc[1][1], 0, 0, 0);
    }
    __syncthreads();                     // all As reads done; reuse smem as Cs

#pragma unroll
    for (int mi = 0; mi < 2; ++mi)
#pragma unroll
        for (int ni = 0; ni < 2; ++ni) {
            int n = w * 64 + ni * 32 + l31;
#pragma unroll
            for (int reg = 0; reg < 16; ++reg) {
                int rr = (reg & 3) + 8 * (reg >> 2) + 4 * lh;
                Cs[(mi * 32 + rr) * D_DIM + n] = acc[mi][ni][reg];
            }
        }
    __syncthreads();

    // scan: thread d handles 8 chunks of 8 along t
    int d = tid;
#pragma unroll
    for (int cl = 0; cl < 8; ++cl) {
        float a = 0.f;
#pragma unroll
        for (int j = 0; j < 8; ++j) {
            int tl = cl * 8 + j;
            int gt = mt * 64 + tl;
            float v = (gt == 0) ? 0.f : Cs[tl * D_DIM + d];
            a = GAMMA_F * a + v;
            loc[(size_t)gt * D_DIM + d] = a;
        }
        carry[(size_t)(mt * 8 + cl) * D_DIM + d] = a;
    }
}

// ---------- K4: S2 scramble-scatter with incremental carry prefix ----------
// Block: q = bid&7 (o const!), dc0 = (bid>>3)*64. Covers S2 rows [q*256, q*256+256),
// cols [dc0, dc0+64). P[dcol] updated incrementally; LDS transpose -> coalesced writes.
__global__ __launch_bounds__(256) void k_S2P(const float* __restrict__ loc,
                                             const float* __restrict__ carry,
                                             float* __restrict__ S2) {
    __shared__ float buf[64 * 256];      // 64 KB: [i=dcol-dc0][r]
    int q = blockIdx.x & 7;
    int dc0 = (blockIdx.x >> 3) * 64;
    int r = threadIdx.x;
    const float g8 = 0.43046721f;                 // 0.9^8
    const float log2g = -0.15200309344504995f;    // log2(0.9)
    float gp = exp2f((float)(q + 1) * log2g);     // gamma^(q+1)

    // warmup: P = sum_{j<dc0} g8^{dc0-1-j} carry[j]  (truncate to last 32)
    float P = 0.f;
    int j0 = dc0 - 32; if (j0 < 0) j0 = 0;
    for (int j = j0; j < dc0; ++j)
        P = P * g8 + carry[(size_t)j * D_DIM + r];

    for (int i = 0; i < 64; ++i) {
        int dcol = dc0 + i;
        int tp = dcol * 8 + q;
        int src = (tp == 0) ? 1 : tp;             // S[0] = A[1]
        float Aval = loc[(size_t)src * D_DIM + r] + gp * P;
        buf[i * 256 + r] = Aval;
        P = P * g8 + carry[(size_t)dcol * D_DIM + r];
    }
    __syncthreads();

    // write S2 row (q*256 + r), cols dc0..dc0+63 (contiguous 256 B per thread)
    float* dst = S2 + (size_t)(q * 256 + r) * D_DIM + dc0;
#pragma unroll
    for (int i4 = 0; i4 < 16; ++i4) {
        float4 v;
        v.x = buf[(i4 * 4 + 0) * 256 + r];
        v.y = buf[(i4 * 4 + 1) * 256 + r];
        v.z = buf[(i4 * 4 + 2) * 256 + r];
        v.w = buf[(i4 * 4 + 3) * 256 + r];
        *(float4*)(dst + i4 * 4) = v;
    }
}

// ---------- K5: out = (xbf @ WqT^T) * S2  (R3's proven 512-block form) ----------
__global__ __launch_bounds__(256) void k_qgemm(const ushort* __restrict__ xbf,
                                               const ushort* __restrict__ WqT,
                                               const float* __restrict__ S2,
                                               float* __restrict__ out) {
    __shared__ ushort As[8 * 128 * 8];   // 16 KB
    __shared__ ushort Bs[8 * 128 * 8];   // 16 KB
    int bid = blockIdx.x;
    int mb = bid >> 1;           // 0..255  (M tile)
    int nb = bid & 1;            // 0..1    (N tile)
    int tid = threadIdx.x;
    int lane = tid & 63, w = tid >> 6;
    int wr = w >> 1, wc = w & 1;
    int l31 = lane & 31, lh = lane >> 5;

    f32x16 acc[2][2];
#pragma unroll
    for (int i = 0; i < 2; ++i)
#pragma unroll
        for (int j = 0; j < 2; ++j)
#pragma unroll
            for (int e = 0; e < 16; ++e) acc[i][j][e] = 0.f;

    int r = tid >> 1;            // 0..127 staging row
    int h0 = tid & 1;            // k-half (32 each)
    const ushort* ag = xbf + (size_t)(mb * 128 + r) * D_DIM + h0 * 32;
    const ushort* bg = WqT + (size_t)(nb * 128 + r) * D_DIM + h0 * 32;

    for (int kb = 0; kb < 4; ++kb) {
#pragma unroll
        for (int j = 0; j < 4; ++j) {
            bf16x8 av = *(const bf16x8*)(ag + kb * 64 + j * 8);
            *(bf16x8*)&As[((h0 * 4 + j) * 128 + r) * 8] = av;
            bf16x8 bv = *(const bf16x8*)(bg + kb * 64 + j * 8);
            *(bf16x8*)&Bs[((h0 * 4 + j) * 128 + r) * 8] = bv;
        }
        __syncthreads();
#pragma unroll
        for (int s = 0; s < 4; ++s) {
            int c0 = (s * 2 + lh) * 128;
            bf16x8 a0 = *(bf16x8*)&As[(c0 + wr * 64 + l31) * 8];
            bf16x8 a1 = *(bf16x8*)&As[(c0 + wr * 64 + 32 + l31) * 8];
            bf16x8 b0 = *(bf16x8*)&Bs[(c0 + wc * 64 + l31) * 8];
            bf16x8 b1 = *(bf16x8*)&Bs[(c0 + wc * 64 + 32 + l31) * 8];
            acc[0][0] = __builtin_amdgcn_mfma_f32_32x32x16_bf16(a0, b0, acc[0][0], 0, 0, 0);
            acc[0][1] = __builtin_amdgcn_mfma_f32_32x32x16_bf16(a0, b1, acc[0][1], 0, 0, 0);
            acc[1][0] = __builtin_amdgcn_mfma_f32_32x32x16_bf16(a1, b0, acc[1][0], 0, 0, 0);
            acc[1][1] = __builtin_amdgcn_mfma_f32_32x32x16_bf16(a1, b1, acc[1][1], 0, 0, 0);
        }
        __syncthreads();
    }

    int t_base = (mb & 15) * 128;
    size_t row_base = (size_t)mb * 128;
#pragma unroll
    for (int mi = 0; mi < 2; ++mi) {
#pragma unroll
        for (int ni = 0; ni < 2; ++ni) {
            int gn = nb * 128 + wc * 64 + ni * 32 + l31;
#pragma unroll
            for (int reg = 0; reg < 16; ++reg) {
                int rr = (reg & 3) + 8 * (reg >> 2) + 4 * lh;
                int m = wr * 64 + mi * 32 + rr;
                float s2v = S2[(size_t)(t_base + m) * D_DIM + gn];
                out[(row_base + m) * D_DIM + gn] = acc[mi][ni][reg] * s2v;
            }
        }
    }
}

extern "C" void kernel_launch(void* const* d_in, const int* in_sizes, int n_in,
                              void* d_out, int out_size, void* d_ws, size_t ws_size,
                              hipStream_t stream) {
    const float* x  = (const float*)d_in[0];
    const float* Wq = (const float*)d_in[1];
    const float* Wk = (const float*)d_in[2];
    const float* Wv = (const float*)d_in[3];
    float* out = (float*)d_out;

    // workspace layout
    float* ws = (float*)d_ws;
    float* loc    = ws;                        // 524288 f
    float* S2     = loc + 524288;              // 524288 f
    float* wv_sum = S2 + 524288;               // 256 f
    float* carry  = wv_sum + 256;              // 65536 f (256 chunks x 256)
    ushort* WqT   = (ushort*)(carry + 65536);  // 65536 us
    ushort* WkT   = WqT + 65536;               // 65536 us
    ushort* ybf   = WkT + 65536;               // 524288 us
    ushort* xbf   = ybf + 524288;              // 8388608 us

    k_prep<<<36, 256, 0, stream>>>(Wq, Wk, Wv, WqT, WkT, wv_sum);
    k_y<<<T_LEN, 256, 0, stream>>>(x, wv_sum, ybf, xbf);
    k_gs<<<32, 256, 0, stream>>>(ybf, WkT, loc, carry);
    k_S2P<<<32, 256, 0, stream>>>(loc, carry, S2);
    k_qgemm<<<(B_DIM * T_LEN / 128) * 2, 256, 0, stream>>>(xbf, WqT, S2, out);
}

// Round 7
// 130.694 us; speedup vs baseline: 1.0345x; 1.0345x over previous
//
#include <hip/hip_runtime.h>
#include <hip/hip_bf16.h>
#include <math.h>

// Problem: B=16, T=2048, D=256, gamma=0.9
// out[b,t,d] = S2[t,d] * (x@Wq)[b,t,d]
// S2[t,d] = S[8d + (t>>8)][t&255]   (reshape-scramble)
// S[t>=1] = A[t], S[0] = A[1],  A[t] = gamma*A[t-1] + g[t], A[0]=0 (g[0] := 0)
// g = y @ Wk,  y[t,:] = sum_b w[b,t]*x[b,t,:],  w[b,t] = x[b,t,:] . rowsum(Wv)
//
// R7: R3's proven 6-kernel structure, minus the xbf intermediate (33.5 MB HBM
// write + read): k_qgemm stages A directly from f32 x (L3-hot after k_y) with
// inline RNE bf16 convert. Scan pair = R5's more-parallel 256x8 chunks.

#define GAMMA_F 0.9f
#define T_LEN 2048
#define D_DIM 256
#define B_DIM 16

typedef __attribute__((ext_vector_type(8))) short bf16x8;
typedef __attribute__((ext_vector_type(16))) float f32x16;

__device__ inline ushort f2bf(float f) {
    union { float f; unsigned u; } v; v.f = f;
    unsigned r = (v.u + 0x7FFFu + ((v.u >> 16) & 1u)) >> 16;  // RNE
    return (ushort)r;
}

// ---------- K1: prep — WqT, WkT (bf16 [n][k]) + wv_sum ----------
__global__ __launch_bounds__(256) void k_prep(const float* __restrict__ Wq,
                                              const float* __restrict__ Wk,
                                              const float* __restrict__ Wv,
                                              ushort* __restrict__ WqT,
                                              ushort* __restrict__ WkT,
                                              float* __restrict__ wv_sum) {
    int bid = blockIdx.x;
    int tid = threadIdx.x;
    if (bid < 32) {
        __shared__ float tile[64][68];
        const float* W = (bid < 16) ? Wq : Wk;
        ushort* WT = (bid < 16) ? WqT : WkT;
        int b = bid & 15;
        int k0 = (b & 3) * 64;
        int n0 = (b >> 2) * 64;
        int r = tid >> 4;            // 0..15
        int c4 = (tid & 15) * 4;     // 0..60
#pragma unroll
        for (int i = 0; i < 4; ++i) {
            float4 v = *(const float4*)(W + (size_t)(k0 + r + 16 * i) * D_DIM + n0 + c4);
            *(float4*)&tile[r + 16 * i][c4] = v;
        }
        __syncthreads();
        int n = tid >> 2;            // 0..63
        int j0 = (tid & 3) * 16;     // 0..48
        ushort tmp[16];
#pragma unroll
        for (int i = 0; i < 16; ++i) tmp[i] = f2bf(tile[j0 + i][n]);
        ushort* dst = WT + (size_t)(n0 + n) * D_DIM + k0 + j0;
#pragma unroll
        for (int i = 0; i < 16; ++i) dst[i] = tmp[i];
    } else {
        int j = (bid - 32) * 64 + (tid >> 2);
        int q = tid & 3;
        const float4* row4 = (const float4*)(Wv + (size_t)j * D_DIM + q * 64);
        float s = 0.f;
#pragma unroll
        for (int i = 0; i < 16; ++i) {
            float4 v = row4[i];
            s += v.x + v.y + v.z + v.w;
        }
        s += __shfl_xor(s, 1, 64);
        s += __shfl_xor(s, 2, 64);
        if (q == 0) wv_sum[j] = s;
    }
}

// ---------- K2: y (bf16) — single streaming pass over x ----------
__global__ __launch_bounds__(256) void k_y(const float* __restrict__ x,
                                           const float* __restrict__ wv_sum,
                                           ushort* __restrict__ ybf) {
    int t = blockIdx.x;
    int d = threadIdx.x;
    float wvd = wv_sum[d];
    float xr[B_DIM];
#pragma unroll
    for (int b = 0; b < B_DIM; ++b)
        xr[b] = x[((size_t)b * T_LEN + t) * D_DIM + d];

    __shared__ float red[B_DIM][4];
    int wave = d >> 6, lane = d & 63;
#pragma unroll
    for (int b = 0; b < B_DIM; ++b) {
        float p = xr[b] * wvd;
        for (int o = 32; o > 0; o >>= 1) p += __shfl_down(p, o, 64);
        if (lane == 0) red[b][wave] = p;
    }
    __syncthreads();
    float yv = 0.f;
#pragma unroll
    for (int b = 0; b < B_DIM; ++b) {
        float wb = red[b][0] + red[b][1] + red[b][2] + red[b][3];
        yv += wb * xr[b];
    }
    ybf[(size_t)t * D_DIM + d] = f2bf(yv);
}

// ---------- K3: g = ybf @ WkT^T  (bf16 MFMA, 64x64 tile, LDS-staged) ----------
__global__ __launch_bounds__(256) void k_gmm(const ushort* __restrict__ ybf,
                                             const ushort* __restrict__ WkT,
                                             float* __restrict__ g) {
    __shared__ ushort As[32 * 64 * 8];   // 32 KB  [s2h][row^swz][8]
    __shared__ ushort Bs[32 * 64 * 8];   // 32 KB
    int mt = blockIdx.x >> 2;            // 0..31 (t tile)
    int nt = blockIdx.x & 3;             // 0..3  (n tile)
    int tid = threadIdx.x, lane = tid & 63, w = tid >> 6;
    int wr = w >> 1, wc = w & 1, l31 = lane & 31, lh = lane >> 5;

#pragma unroll
    for (int i = 0; i < 8; ++i) {
        int slot = tid + 256 * i;        // 0..2047
        int r = slot >> 5;               // 0..63
        int s2h = slot & 31;             // 0..31
        int rs = r ^ (s2h & 7);          // bank swizzle
        *(bf16x8*)&As[(s2h * 64 + rs) * 8] =
            *(const bf16x8*)&ybf[(size_t)(mt * 64 + r) * D_DIM + s2h * 8];
        *(bf16x8*)&Bs[(s2h * 64 + rs) * 8] =
            *(const bf16x8*)&WkT[(size_t)(nt * 64 + r) * D_DIM + s2h * 8];
    }
    __syncthreads();

    f32x16 acc;
#pragma unroll
    for (int e = 0; e < 16; ++e) acc[e] = 0.f;
#pragma unroll
    for (int s = 0; s < 16; ++s) {
        int s2h = s * 2 + lh;
        int ra = (wr * 32 + l31) ^ (s2h & 7);
        int rb = (wc * 32 + l31) ^ (s2h & 7);
        bf16x8 a = *(bf16x8*)&As[(s2h * 64 + ra) * 8];
        bf16x8 b = *(bf16x8*)&Bs[(s2h * 64 + rb) * 8];
        acc = __builtin_amdgcn_mfma_f32_32x32x16_bf16(a, b, acc, 0, 0, 0);
    }
#pragma unroll
    for (int reg = 0; reg < 16; ++reg) {
        int rr = (reg & 3) + 8 * (reg >> 2) + 4 * lh;
        g[(size_t)(mt * 64 + wr * 32 + rr) * D_DIM + nt * 64 + wc * 32 + l31] = acc[reg];
    }
}

// ---------- K4: local scan, 256 chunks of 8 ----------
__global__ void k_scanA(const float* __restrict__ g, float* __restrict__ loc,
                        float* __restrict__ carry) {
    int c = blockIdx.x;      // 0..255
    int d = threadIdx.x;     // 0..255
    float v[8];
#pragma unroll
    for (int j = 0; j < 8; ++j) {
        int t = c * 8 + j;
        v[j] = (t == 0) ? 0.f : g[(size_t)t * D_DIM + d];
    }
    float acc = 0.f;
#pragma unroll
    for (int j = 0; j < 8; ++j) {
        acc = GAMMA_F * acc + v[j];
        loc[(size_t)(c * 8 + j) * D_DIM + d] = acc;
    }
    carry[(size_t)c * D_DIM + d] = acc;
}

// ---------- K5: A[t] = loc + gamma^(o+1)*P[c] (P truncated, 32 terms); scatter ----------
__global__ __launch_bounds__(256) void k_S2P(const float* __restrict__ loc,
                                             const float* __restrict__ carry,
                                             float* __restrict__ S2) {
    int tp = blockIdx.x;
    int r = threadIdx.x;
    int src = (tp == 0) ? 1 : tp;           // S[0] = A[1]
    int c = src >> 3, o = src & 7;
    const float g8 = 0.43046721f;           // 0.9^8
    int j0 = c - 32; if (j0 < 0) j0 = 0;    // 0.43^32 ~ 2e-12: exact to f32
    float p = 0.f;
    for (int j = j0; j < c; ++j)
        p = p * g8 + carry[(size_t)j * D_DIM + r];
    const float log2g = -0.15200309344504995f;  // log2(0.9)
    float gp = exp2f((float)(o + 1) * log2g);
    float Aval = loc[(size_t)src * D_DIM + r] + gp * p;
    int trow = ((tp & 7) << 8) + r;
    int dcol = tp >> 3;
    S2[(size_t)trow * D_DIM + dcol] = Aval;
}

// ---------- K6: out = (x @ Wq) * S2 — A staged from f32 x with inline cvt ----------
__global__ __launch_bounds__(256) void k_qgemm(const float* __restrict__ x,
                                               const ushort* __restrict__ WqT,
                                               const float* __restrict__ S2,
                                               float* __restrict__ out) {
    __shared__ ushort As[8 * 128 * 8];   // 16 KB
    __shared__ ushort Bs[8 * 128 * 8];   // 16 KB
    int bid = blockIdx.x;
    int mb = bid >> 1;           // 0..255  (M tile)
    int nb = bid & 1;            // 0..1    (N tile)
    int tid = threadIdx.x;
    int lane = tid & 63, w = tid >> 6;
    int wr = w >> 1, wc = w & 1;
    int l31 = lane & 31, lh = lane >> 5;

    f32x16 acc[2][2];
#pragma unroll
    for (int i = 0; i < 2; ++i)
#pragma unroll
        for (int j = 0; j < 2; ++j)
#pragma unroll
            for (int e = 0; e < 16; ++e) acc[i][j][e] = 0.f;

    int r = tid >> 1;            // 0..127 staging row
    int h0 = tid & 1;            // k-half (32 each)
    const float* ag = x + (size_t)(mb * 128 + r) * D_DIM + h0 * 32;
    const ushort* bg = WqT + (size_t)(nb * 128 + r) * D_DIM + h0 * 32;

    for (int kb = 0; kb < 4; ++kb) {
#pragma unroll
        for (int j = 0; j < 4; ++j) {
            float4 v0 = *(const float4*)(ag + kb * 64 + j * 8);
            float4 v1 = *(const float4*)(ag + kb * 64 + j * 8 + 4);
            ushort4 p0, p1;
            p0.x = f2bf(v0.x); p0.y = f2bf(v0.y); p0.z = f2bf(v0.z); p0.w = f2bf(v0.w);
            p1.x = f2bf(v1.x); p1.y = f2bf(v1.y); p1.z = f2bf(v1.z); p1.w = f2bf(v1.w);
            *(ushort4*)&As[((h0 * 4 + j) * 128 + r) * 8] = p0;
            *(ushort4*)&As[((h0 * 4 + j) * 128 + r) * 8 + 4] = p1;
            bf16x8 bv = *(const bf16x8*)(bg + kb * 64 + j * 8);
            *(bf16x8*)&Bs[((h0 * 4 + j) * 128 + r) * 8] = bv;
        }
        __syncthreads();
#pragma unroll
        for (int s = 0; s < 4; ++s) {
            int c0 = (s * 2 + lh) * 128;
            bf16x8 a0 = *(bf16x8*)&As[(c0 + wr * 64 + l31) * 8];
            bf16x8 a1 = *(bf16x8*)&As[(c0 + wr * 64 + 32 + l31) * 8];
            bf16x8 b0 = *(bf16x8*)&Bs[(c0 + wc * 64 + l31) * 8];
            bf16x8 b1 = *(bf16x8*)&Bs[(c0 + wc * 64 + 32 + l31) * 8];
            acc[0][0] = __builtin_amdgcn_mfma_f32_32x32x16_bf16(a0, b0, acc[0][0], 0, 0, 0);
            acc[0][1] = __builtin_amdgcn_mfma_f32_32x32x16_bf16(a0, b1, acc[0][1], 0, 0, 0);
            acc[1][0] = __builtin_amdgcn_mfma_f32_32x32x16_bf16(a1, b0, acc[1][0], 0, 0, 0);
            acc[1][1] = __builtin_amdgcn_mfma_f32_32x32x16_bf16(a1, b1, acc[1][1], 0, 0, 0);
        }
        __syncthreads();
    }

    int t_base = (mb & 15) * 128;
    size_t row_base = (size_t)mb * 128;
#pragma unroll
    for (int mi = 0; mi < 2; ++mi) {
#pragma unroll
        for (int ni = 0; ni < 2; ++ni) {
            int gn = nb * 128 + wc * 64 + ni * 32 + l31;
#pragma unroll
            for (int reg = 0; reg < 16; ++reg) {
                int rr = (reg & 3) + 8 * (reg >> 2) + 4 * lh;
                int m = wr * 64 + mi * 32 + rr;
                float s2v = S2[(size_t)(t_base + m) * D_DIM + gn];
                out[(row_base + m) * D_DIM + gn] = acc[mi][ni][reg] * s2v;
            }
        }
    }
}

extern "C" void kernel_launch(void* const* d_in, const int* in_sizes, int n_in,
                              void* d_out, int out_size, void* d_ws, size_t ws_size,
                              hipStream_t stream) {
    const float* x  = (const float*)d_in[0];
    const float* Wq = (const float*)d_in[1];
    const float* Wk = (const float*)d_in[2];
    const float* Wv = (const float*)d_in[3];
    float* out = (float*)d_out;

    // workspace layout
    float* ws = (float*)d_ws;
    float* g      = ws;                        // 524288 f
    float* loc    = g + 524288;                // 524288 f
    float* S2     = loc + 524288;              // 524288 f
    float* wv_sum = S2 + 524288;               // 256 f
    float* carry  = wv_sum + 256;              // 65536 f (256 chunks x 256)
    ushort* WqT   = (ushort*)(carry + 65536);  // 65536 us
    ushort* WkT   = WqT + 65536;               // 65536 us
    ushort* ybf   = WkT + 65536;               // 524288 us

    k_prep<<<36, 256, 0, stream>>>(Wq, Wk, Wv, WqT, WkT, wv_sum);
    k_y<<<T_LEN, 256, 0, stream>>>(x, wv_sum, ybf);
    k_gmm<<<128, 256, 0, stream>>>(ybf, WkT, g);
    k_scanA<<<256, 256, 0, stream>>>(g, loc, carry);
    k_S2P<<<T_LEN, 256, 0, stream>>>(loc, carry, S2);
    k_qgemm<<<(B_DIM * T_LEN / 128) * 2, 256, 0, stream>>>(x, WqT, S2, out);
}

// Round 8
// 128.605 us; speedup vs baseline: 1.0513x; 1.0162x over previous
//
#include <hip/hip_runtime.h>
#include <hip/hip_bf16.h>
#include <math.h>

// Problem: B=16, T=2048, D=256, gamma=0.9
// out[b,t,d] = S2[t,d] * (x@Wq)[b,t,d]
// S2[t,d] = S[8d + (t>>8)][t&255]   (reshape-scramble)
// S[t>=1] = A[t], S[0] = A[1],  A[t] = gamma*A[t-1] + g[t], A[0]=0 (g[0] := 0)
// g = y @ Wk,  y[t,:] = sum_b w[b,t]*x[b,t,:],  w[b,t] = x[b,t,:] . rowsum(Wv)
//
// R8: R7 pipeline with k_scanA fused into the g-GEMM at full 128-block
// parallelism (g never touches memory; loc/carry written in-block).
// 5 kernels: prep -> y -> gs -> S2P -> qgemm.

#define GAMMA_F 0.9f
#define T_LEN 2048
#define D_DIM 256
#define B_DIM 16

typedef __attribute__((ext_vector_type(8))) short bf16x8;
typedef __attribute__((ext_vector_type(16))) float f32x16;

__device__ inline ushort f2bf(float f) {
    union { float f; unsigned u; } v; v.f = f;
    unsigned r = (v.u + 0x7FFFu + ((v.u >> 16) & 1u)) >> 16;  // RNE
    return (ushort)r;
}

// ---------- K1: prep — WqT, WkT (bf16 [n][k]) + wv_sum ----------
__global__ __launch_bounds__(256) void k_prep(const float* __restrict__ Wq,
                                              const float* __restrict__ Wk,
                                              const float* __restrict__ Wv,
                                              ushort* __restrict__ WqT,
                                              ushort* __restrict__ WkT,
                                              float* __restrict__ wv_sum) {
    int bid = blockIdx.x;
    int tid = threadIdx.x;
    if (bid < 32) {
        __shared__ float tile[64][68];
        const float* W = (bid < 16) ? Wq : Wk;
        ushort* WT = (bid < 16) ? WqT : WkT;
        int b = bid & 15;
        int k0 = (b & 3) * 64;
        int n0 = (b >> 2) * 64;
        int r = tid >> 4;            // 0..15
        int c4 = (tid & 15) * 4;     // 0..60
#pragma unroll
        for (int i = 0; i < 4; ++i) {
            float4 v = *(const float4*)(W + (size_t)(k0 + r + 16 * i) * D_DIM + n0 + c4);
            *(float4*)&tile[r + 16 * i][c4] = v;
        }
        __syncthreads();
        int n = tid >> 2;            // 0..63
        int j0 = (tid & 3) * 16;     // 0..48
        ushort tmp[16];
#pragma unroll
        for (int i = 0; i < 16; ++i) tmp[i] = f2bf(tile[j0 + i][n]);
        ushort* dst = WT + (size_t)(n0 + n) * D_DIM + k0 + j0;
#pragma unroll
        for (int i = 0; i < 16; ++i) dst[i] = tmp[i];
    } else {
        int j = (bid - 32) * 64 + (tid >> 2);
        int q = tid & 3;
        const float4* row4 = (const float4*)(Wv + (size_t)j * D_DIM + q * 64);
        float s = 0.f;
#pragma unroll
        for (int i = 0; i < 16; ++i) {
            float4 v = row4[i];
            s += v.x + v.y + v.z + v.w;
        }
        s += __shfl_xor(s, 1, 64);
        s += __shfl_xor(s, 2, 64);
        if (q == 0) wv_sum[j] = s;
    }
}

// ---------- K2: y (bf16) — single streaming pass over x ----------
__global__ __launch_bounds__(256) void k_y(const float* __restrict__ x,
                                           const float* __restrict__ wv_sum,
                                           ushort* __restrict__ ybf) {
    int t = blockIdx.x;
    int d = threadIdx.x;
    float wvd = wv_sum[d];
    float xr[B_DIM];
#pragma unroll
    for (int b = 0; b < B_DIM; ++b)
        xr[b] = x[((size_t)b * T_LEN + t) * D_DIM + d];

    __shared__ float red[B_DIM][4];
    int wave = d >> 6, lane = d & 63;
#pragma unroll
    for (int b = 0; b < B_DIM; ++b) {
        float p = xr[b] * wvd;
        for (int o = 32; o > 0; o >>= 1) p += __shfl_down(p, o, 64);
        if (lane == 0) red[b][wave] = p;
    }
    __syncthreads();
    float yv = 0.f;
#pragma unroll
    for (int b = 0; b < B_DIM; ++b) {
        float wb = red[b][0] + red[b][1] + red[b][2] + red[b][3];
        yv += wb * xr[b];
    }
    ybf[(size_t)t * D_DIM + d] = f2bf(yv);
}

// ---------- K3: fused g-GEMM + local scan (128 blocks, full parallelism) ----------
// Block (mt, nt): C = ybf[mt*64..][:] @ WkT[nt*64..][:]^T (64x64), round-trip
// through LDS (aliased over As), then 8-step chunk scans along t -> loc, carry.
__global__ __launch_bounds__(256) void k_gs(const ushort* __restrict__ ybf,
                                            const ushort* __restrict__ WkT,
                                            float* __restrict__ loc,
                                            float* __restrict__ carry) {
    __shared__ ushort As[32 * 64 * 8];   // 32 KB  [s2h][row^swz][8]
    __shared__ ushort Bs[32 * 64 * 8];   // 32 KB
    float* Cs = (float*)As;              // 16 KB alias: [tl=0..63][dl=0..63]
    int mt = blockIdx.x >> 2;            // 0..31 (t tile)
    int nt = blockIdx.x & 3;             // 0..3  (n tile)
    int tid = threadIdx.x, lane = tid & 63, w = tid >> 6;
    int wr = w >> 1, wc = w & 1, l31 = lane & 31, lh = lane >> 5;

#pragma unroll
    for (int i = 0; i < 8; ++i) {
        int slot = tid + 256 * i;        // 0..2047
        int r = slot >> 5;               // 0..63
        int s2h = slot & 31;             // 0..31
        int rs = r ^ (s2h & 7);          // bank swizzle
        *(bf16x8*)&As[(s2h * 64 + rs) * 8] =
            *(const bf16x8*)&ybf[(size_t)(mt * 64 + r) * D_DIM + s2h * 8];
        *(bf16x8*)&Bs[(s2h * 64 + rs) * 8] =
            *(const bf16x8*)&WkT[(size_t)(nt * 64 + r) * D_DIM + s2h * 8];
    }
    __syncthreads();

    f32x16 acc;
#pragma unroll
    for (int e = 0; e < 16; ++e) acc[e] = 0.f;
#pragma unroll
    for (int s = 0; s < 16; ++s) {
        int s2h = s * 2 + lh;
        int ra = (wr * 32 + l31) ^ (s2h & 7);
        int rb = (wc * 32 + l31) ^ (s2h & 7);
        bf16x8 a = *(bf16x8*)&As[(s2h * 64 + ra) * 8];
        bf16x8 b = *(bf16x8*)&Bs[(s2h * 64 + rb) * 8];
        acc = __builtin_amdgcn_mfma_f32_32x32x16_bf16(a, b, acc, 0, 0, 0);
    }
    __syncthreads();                     // all As/Bs reads done; alias Cs

#pragma unroll
    for (int reg = 0; reg < 16; ++reg) {
        int rr = (reg & 3) + 8 * (reg >> 2) + 4 * lh;
        Cs[(wr * 32 + rr) * 64 + wc * 32 + l31] = acc[reg];
    }
    __syncthreads();

    // scan: 512 (cl, dl) tasks over 256 threads
#pragma unroll
    for (int half = 0; half < 2; ++half) {
        int task = half * 256 + tid;     // 0..511
        int dl = task & 63;              // 0..63
        int cl = task >> 6;              // 0..7
        float a = 0.f;
#pragma unroll
        for (int j = 0; j < 8; ++j) {
            int tl = cl * 8 + j;
            int gt = mt * 64 + tl;
            float v = (gt == 0) ? 0.f : Cs[tl * 64 + dl];
            a = GAMMA_F * a + v;
            loc[(size_t)gt * D_DIM + nt * 64 + dl] = a;
        }
        carry[(size_t)(mt * 8 + cl) * D_DIM + nt * 64 + dl] = a;
    }
}

// ---------- K4: A[t] = loc + gamma^(o+1)*P[c] (P truncated, 32 terms); scatter ----------
__global__ __launch_bounds__(256) void k_S2P(const float* __restrict__ loc,
                                             const float* __restrict__ carry,
                                             float* __restrict__ S2) {
    int tp = blockIdx.x;
    int r = threadIdx.x;
    int src = (tp == 0) ? 1 : tp;           // S[0] = A[1]
    int c = src >> 3, o = src & 7;
    const float g8 = 0.43046721f;           // 0.9^8
    int j0 = c - 32; if (j0 < 0) j0 = 0;    // 0.43^32 ~ 2e-12: exact to f32
    float p = 0.f;
    for (int j = j0; j < c; ++j)
        p = p * g8 + carry[(size_t)j * D_DIM + r];
    const float log2g = -0.15200309344504995f;  // log2(0.9)
    float gp = exp2f((float)(o + 1) * log2g);
    float Aval = loc[(size_t)src * D_DIM + r] + gp * p;
    int trow = ((tp & 7) << 8) + r;
    int dcol = tp >> 3;
    S2[(size_t)trow * D_DIM + dcol] = Aval;
}

// ---------- K5: out = (x @ Wq) * S2 — A staged from f32 x with inline cvt ----------
__global__ __launch_bounds__(256) void k_qgemm(const float* __restrict__ x,
                                               const ushort* __restrict__ WqT,
                                               const float* __restrict__ S2,
                                               float* __restrict__ out) {
    __shared__ ushort As[8 * 128 * 8];   // 16 KB
    __shared__ ushort Bs[8 * 128 * 8];   // 16 KB
    int bid = blockIdx.x;
    int mb = bid >> 1;           // 0..255  (M tile)
    int nb = bid & 1;            // 0..1    (N tile)
    int tid = threadIdx.x;
    int lane = tid & 63, w = tid >> 6;
    int wr = w >> 1, wc = w & 1;
    int l31 = lane & 31, lh = lane >> 5;

    f32x16 acc[2][2];
#pragma unroll
    for (int i = 0; i < 2; ++i)
#pragma unroll
        for (int j = 0; j < 2; ++j)
#pragma unroll
            for (int e = 0; e < 16; ++e) acc[i][j][e] = 0.f;

    int r = tid >> 1;            // 0..127 staging row
    int h0 = tid & 1;            // k-half (32 each)
    const float* ag = x + (size_t)(mb * 128 + r) * D_DIM + h0 * 32;
    const ushort* bg = WqT + (size_t)(nb * 128 + r) * D_DIM + h0 * 32;

    for (int kb = 0; kb < 4; ++kb) {
#pragma unroll
        for (int j = 0; j < 4; ++j) {
            float4 v0 = *(const float4*)(ag + kb * 64 + j * 8);
            float4 v1 = *(const float4*)(ag + kb * 64 + j * 8 + 4);
            ushort4 p0, p1;
            p0.x = f2bf(v0.x); p0.y = f2bf(v0.y); p0.z = f2bf(v0.z); p0.w = f2bf(v0.w);
            p1.x = f2bf(v1.x); p1.y = f2bf(v1.y); p1.z = f2bf(v1.z); p1.w = f2bf(v1.w);
            *(ushort4*)&As[((h0 * 4 + j) * 128 + r) * 8] = p0;
            *(ushort4*)&As[((h0 * 4 + j) * 128 + r) * 8 + 4] = p1;
            bf16x8 bv = *(const bf16x8*)(bg + kb * 64 + j * 8);
            *(bf16x8*)&Bs[((h0 * 4 + j) * 128 + r) * 8] = bv;
        }
        __syncthreads();
#pragma unroll
        for (int s = 0; s < 4; ++s) {
            int c0 = (s * 2 + lh) * 128;
            bf16x8 a0 = *(bf16x8*)&As[(c0 + wr * 64 + l31) * 8];
            bf16x8 a1 = *(bf16x8*)&As[(c0 + wr * 64 + 32 + l31) * 8];
            bf16x8 b0 = *(bf16x8*)&Bs[(c0 + wc * 64 + l31) * 8];
            bf16x8 b1 = *(bf16x8*)&Bs[(c0 + wc * 64 + 32 + l31) * 8];
            acc[0][0] = __builtin_amdgcn_mfma_f32_32x32x16_bf16(a0, b0, acc[0][0], 0, 0, 0);
            acc[0][1] = __builtin_amdgcn_mfma_f32_32x32x16_bf16(a0, b1, acc[0][1], 0, 0, 0);
            acc[1][0] = __builtin_amdgcn_mfma_f32_32x32x16_bf16(a1, b0, acc[1][0], 0, 0, 0);
            acc[1][1] = __builtin_amdgcn_mfma_f32_32x32x16_bf16(a1, b1, acc[1][1], 0, 0, 0);
        }
        __syncthreads();
    }

    int t_base = (mb & 15) * 128;
    size_t row_base = (size_t)mb * 128;
#pragma unroll
    for (int mi = 0; mi < 2; ++mi) {
#pragma unroll
        for (int ni = 0; ni < 2; ++ni) {
            int gn = nb * 128 + wc * 64 + ni * 32 + l31;
#pragma unroll
            for (int reg = 0; reg < 16; ++reg) {
                int rr = (reg & 3) + 8 * (reg >> 2) + 4 * lh;
                int m = wr * 64 + mi * 32 + rr;
                float s2v = S2[(size_t)(t_base + m) * D_DIM + gn];
                out[(row_base + m) * D_DIM + gn] = acc[mi][ni][reg] * s2v;
            }
        }
    }
}

extern "C" void kernel_launch(void* const* d_in, const int* in_sizes, int n_in,
                              void* d_out, int out_size, void* d_ws, size_t ws_size,
                              hipStream_t stream) {
    const float* x  = (const float*)d_in[0];
    const float* Wq = (const float*)d_in[1];
    const float* Wk = (const float*)d_in[2];
    const float* Wv = (const float*)d_in[3];
    float* out = (float*)d_out;

    // workspace layout
    float* ws = (float*)d_ws;
    float* loc    = ws;                        // 524288 f
    float* S2     = loc + 524288;              // 524288 f
    float* wv_sum = S2 + 524288;               // 256 f
    float* carry  = wv_sum + 256;              // 65536 f (256 chunks x 256)
    ushort* WqT   = (ushort*)(carry + 65536);  // 65536 us
    ushort* WkT   = WqT + 65536;               // 65536 us
    ushort* ybf   = WkT + 65536;               // 524288 us

    k_prep<<<36, 256, 0, stream>>>(Wq, Wk, Wv, WqT, WkT, wv_sum);
    k_y<<<T_LEN, 256, 0, stream>>>(x, wv_sum, ybf);
    k_gs<<<128, 256, 0, stream>>>(ybf, WkT, loc, carry);
    k_S2P<<<T_LEN, 256, 0, stream>>>(loc, carry, S2);
    k_qgemm<<<(B_DIM * T_LEN / 128) * 2, 256, 0, stream>>>(x, WqT, S2, out);
}